// Round 1
// baseline (680.652 us; speedup 1.0000x reference)
//
#include <hip/hip_runtime.h>
#include <cstdint>
#include <cstddef>

// ---------------------------------------------------------------------------
// TensoSDF shape renderer: tri-plane sample + embed -> MLP(129->256->129)
// R2: split sampler / MLP kernels.
//  - planes & lines padded to NCP=40 channels -> 16B gather loads, vector fold
//  - sampler writes mlp_in in MFMA A-fragment order [tile][chunk][row][16B]
//  - MLP kernel: no input staging (direct global A-frags), LDS only for h
//    (32KB, XOR-swizzled, bank-conflict-free) -> 4 blocks/CU
//  - fallback tiers if workspace too small (T1 fused w/ new layout, T2 slow)
// k-map: k in [0,160): k<120 -> feat m=k/40,c=k%40 (c<36 valid, ref 21+m*36+c)
//        120<=k<141 -> embed ref k-120 ; else zero-weight
// ---------------------------------------------------------------------------

using half2v  = __attribute__((ext_vector_type(2))) _Float16;
using half4   = __attribute__((ext_vector_type(4))) _Float16;
using half8   = __attribute__((ext_vector_type(8))) _Float16;
using floatx4 = __attribute__((ext_vector_type(4))) float;

#define NPTS    524288
#define GRES    300
#define NCOMP   36
#define NCP     40
#define SDFD    256
#define IN_CH   129
#define OUT_CH  129
#define TILE_M  64

// workspace layout (bytes), all 16B aligned
#define OFF_W1S 0
#define SZ_W1S  (5*4*256*8*2)               // 81920 : w1 swizzled f16 [c16][n=256][j=8]
#define OFF_W2S (OFF_W1S + SZ_W1S)
#define SZ_W2S  (8*4*144*8*2)               // 73728 : w2 swizzled f16
#define OFF_LT  (OFF_W2S + SZ_W2S)
#define SZ_LT   (3*GRES*NCP*2)              // 72000 : lines ch-last padded f16
#define OFF_PLT (OFF_LT + SZ_LT)
#define SZ_PLT  ((size_t)3*GRES*GRES*NCP*2) // 21.6MB: planes ch-last padded f16
#define OFF_MLP (OFF_PLT + SZ_PLT)
#define SZ_MLP  ((size_t)NPTS*160*2)        // 167.8MB: mlp_in fragment-ordered
#define NEED_T1 ((size_t)OFF_PLT + SZ_PLT)
#define NEED_T0 ((size_t)OFF_MLP + SZ_MLP)

// ---- prep kernels ---------------------------------------------------------

__global__ void prep_planes_k(const float* __restrict__ planes, _Float16* __restrict__ pl_t) {
    int idx = blockIdx.x * 256 + threadIdx.x;           // (m*300+y)*300+x
    if (idx >= 3 * GRES * GRES) return;
    int x = idx % GRES; int t = idx / GRES; int y = t % GRES; int m = t / GRES;
    _Float16* dst = pl_t + (size_t)idx * NCP;
    const float* src = planes + (size_t)m * NCOMP * GRES * GRES + (size_t)y * GRES + x;
    #pragma unroll
    for (int j = 0; j < 5; ++j) {
        half8 o;
        #pragma unroll
        for (int e = 0; e < 8; ++e) {
            int c = j * 8 + e;
            o[e] = (c < NCOMP) ? (_Float16)src[(size_t)c * GRES * GRES] : (_Float16)0.f;
        }
        *(half8*)(dst + j * 8) = o;
    }
}

#define NB_W1 ((5*4*256*8 + 255)/256)      // 160
#define NB_W2 ((8*4*144*8 + 255)/256)      // 144
#define NB_L  ((3*GRES + 255)/256)         // 4
__global__ void prep_small_k(const float* __restrict__ w1, const float* __restrict__ w2,
                             const float* __restrict__ lines,
                             _Float16* __restrict__ w1s, _Float16* __restrict__ w2s,
                             _Float16* __restrict__ l_t) {
    int b = blockIdx.x;
    if (b < NB_W1) {
        int t = b * 256 + threadIdx.x;                   // < 40960 exactly
        int j = t & 7; int n = (t >> 3) & 255; int q = t >> 11;
        int k = q * 8 + j;                               // 0..159
        float v = 0.f;
        if (k < 120) {
            int m = k / 40, c = k % 40;
            if (c < NCOMP) v = w1[n * IN_CH + 21 + m * NCOMP + c];
        } else if (k < 141) {
            v = w1[n * IN_CH + (k - 120)];
        }
        w1s[t] = (_Float16)v;
    } else if (b < NB_W1 + NB_W2) {
        int t = (b - NB_W1) * 256 + threadIdx.x;
        if (t >= 8*4*144*8) return;
        int j = t & 7; int r = t >> 3; int n = r % 144; int q = r / 144;
        int k = q * 8 + j;                               // 0..255
        float v = (n < OUT_CH) ? w2[n * SDFD + k] : 0.f;
        w2s[t] = (_Float16)v;
    } else {
        int idx = (b - NB_W1 - NB_W2) * 256 + threadIdx.x;   // m*300+z
        if (idx >= 3 * GRES) return;
        int z = idx % GRES; int m = idx / GRES;
        _Float16* dst = l_t + (size_t)idx * NCP;
        const float* src = lines + ((size_t)m * NCOMP) * GRES + z;
        #pragma unroll
        for (int c = 0; c < NCOMP; ++c) dst[c] = (_Float16)src[(size_t)c * GRES];
        dst[36] = dst[37] = dst[38] = dst[39] = (_Float16)0.f;
    }
}

// ---- device helpers -------------------------------------------------------

__device__ __forceinline__ float softplus100(float z) {
    return fmaxf(z, 0.f) + __logf(1.f + __expf(-fabsf(z)));
}

__device__ __forceinline__ void plane_coords(int m, float X, float Y, float Z,
                                             int& x0, int& y0, int& z0,
                                             float& tx, float& ty, float& tz) {
    const float px = (m == 2) ? Y : X;
    const float py = (m == 0) ? Y : Z;
    const float pz = (m == 0) ? Z : ((m == 1) ? Y : X);
    float fx = (px + 1.f) * 0.5f * 299.f;
    float fy = (py + 1.f) * 0.5f * 299.f;
    float fz = (pz + 1.f) * 0.5f * 299.f;
    x0 = (int)floorf(fx); x0 = x0 < 0 ? 0 : (x0 > 298 ? 298 : x0);
    y0 = (int)floorf(fy); y0 = y0 < 0 ? 0 : (y0 > 298 ? 298 : y0);
    z0 = (int)floorf(fz); z0 = z0 < 0 ? 0 : (z0 > 298 ? 298 : z0);
    tx = fx - (float)x0; ty = fy - (float)y0; tz = fz - (float)z0;
}

// fast gather: NCP=40 channel-last layout; corner-pair = 160B contiguous
__device__ __forceinline__ void plane_gather_fast(
    int m, float X, float Y, float Z,
    const _Float16* __restrict__ pl_t, const _Float16* __restrict__ l_t,
    half8 f[5])
{
    int x0, y0, z0; float tx, ty, tz;
    plane_coords(m, X, Y, Z, x0, y0, z0, tx, ty, tz);
    const _Float16 h00 = (_Float16)((1.f - tx) * (1.f - ty));
    const _Float16 h01 = (_Float16)(tx * (1.f - ty));
    const _Float16 h10 = (_Float16)((1.f - tx) * ty);
    const _Float16 h11 = (_Float16)(tx * ty);
    const _Float16 hl0 = (_Float16)(1.f - tz), hl1 = (_Float16)tz;
    const half8 W00 = {h00,h00,h00,h00,h00,h00,h00,h00};
    const half8 W01 = {h01,h01,h01,h01,h01,h01,h01,h01};
    const half8 W10 = {h10,h10,h10,h10,h10,h10,h10,h10};
    const half8 W11 = {h11,h11,h11,h11,h11,h11,h11,h11};
    const half8 WL0 = {hl0,hl0,hl0,hl0,hl0,hl0,hl0,hl0};
    const half8 WL1 = {hl1,hl1,hl1,hl1,hl1,hl1,hl1,hl1};
    const _Float16* r0 = pl_t + ((size_t)(m * GRES + y0) * GRES + x0) * NCP;  // (y0,x0|x0+1)
    const _Float16* r1 = r0 + (size_t)GRES * NCP;                              // (y0+1, ...)
    const _Float16* lb = l_t + (size_t)(m * GRES + z0) * NCP;                  // (z0|z0+1)
    half8 a0[10], a1[10], al[10];
    #pragma unroll
    for (int j = 0; j < 10; ++j) a0[j] = *(const half8*)(r0 + 8 * j);
    #pragma unroll
    for (int j = 0; j < 10; ++j) a1[j] = *(const half8*)(r1 + 8 * j);
    half8 pf[5];
    #pragma unroll
    for (int j = 0; j < 5; ++j)
        pf[j] = a0[j] * W00 + a0[j + 5] * W01 + a1[j] * W10 + a1[j + 5] * W11;
    #pragma unroll
    for (int j = 0; j < 10; ++j) al[j] = *(const half8*)(lb + 8 * j);
    #pragma unroll
    for (int j = 0; j < 5; ++j) {
        half8 lf = al[j] * WL0 + al[j + 5] * WL1;
        f[j] = pf[j] * lf;
    }
}

// slow gather: raw f32 planes/lines (fallback when workspace too small)
__device__ __forceinline__ void plane_gather_slow(
    int m, float X, float Y, float Z,
    const float* __restrict__ planes, const float* __restrict__ lines,
    half8 f[5])
{
    int x0, y0, z0; float tx, ty, tz;
    plane_coords(m, X, Y, Z, x0, y0, z0, tx, ty, tz);
    const float w00 = (1.f - tx) * (1.f - ty), w01 = tx * (1.f - ty);
    const float w10 = (1.f - tx) * ty,         w11 = tx * ty;
    const float lw0 = 1.f - tz, lw1 = tz;
    #pragma unroll
    for (int j = 0; j < 5; ++j) f[j] = (half8){0,0,0,0,0,0,0,0};
    const float* pb = planes + (size_t)m * NCOMP * GRES * GRES;
    #pragma unroll
    for (int c = 0; c < NCOMP; ++c) {
        const float* pc = pb + (size_t)c * GRES * GRES + (size_t)y0 * GRES + x0;
        const float* lc = lines + ((size_t)m * NCOMP + c) * GRES + z0;
        float pf = pc[0] * w00 + pc[1] * w01 + pc[GRES] * w10 + pc[GRES + 1] * w11;
        float lf = lc[0] * lw0 + lc[1] * lw1;
        f[c >> 3][c & 7] = (_Float16)(pf * lf);
    }
}

// embed -> chunks c16=15..19 (k=120..159); zeros beyond k=140
__device__ __forceinline__ void embed_chunks(float X, float Y, float Z, half8 e[5]) {
    const float v3[3] = {X, Y, Z};
    _Float16 s[3][3], c[3][3];
    #pragma unroll
    for (int d = 0; d < 3; ++d) {
        float fm = 1.f;
        #pragma unroll
        for (int q = 0; q < 3; ++q) {
            const float a = v3[d] * fm;
            s[d][q] = (_Float16)__sinf(a);
            c[d][q] = (_Float16)__cosf(a);
            fm *= 2.f;
        }
    }
    const _Float16 z0 = (_Float16)0.f;
    e[0] = (half8){(_Float16)X, (_Float16)Y, (_Float16)Z, s[0][0], s[0][1], s[0][2], s[1][0], s[1][1]};
    e[1] = (half8){s[1][2], s[2][0], s[2][1], s[2][2], c[0][0], c[0][1], c[0][2], c[1][0]};
    e[2] = (half8){c[1][1], c[1][2], c[2][0], c[2][1], c[2][2], z0, z0, z0};
    e[3] = (half8){z0,z0,z0,z0,z0,z0,z0,z0};
    e[4] = (half8){z0,z0,z0,z0,z0,z0,z0,z0};
}

// ---- T0 sampler: gather + embed -> mlp_in (fragment-ordered global) -------
// layout: halfs offset = (tile*1280 + c16*64 + row) * 8 ; tile=gp>>6, row=gp&63

__global__ __launch_bounds__(256, 4)
void sampler_k(const float* __restrict__ xyz,
               const _Float16* __restrict__ pl_t,
               const _Float16* __restrict__ l_t,
               _Float16* __restrict__ mg)
{
    const int tid = threadIdx.x;
    const size_t gp = (size_t)blockIdx.x * TILE_M + (tid >> 2);
    const int sub = tid & 3;
    const float X = xyz[gp * 3 + 0];
    const float Y = xyz[gp * 3 + 1];
    const float Z = xyz[gp * 3 + 2];
    const size_t tile = gp >> 6;
    const int row = (int)(gp & 63);
    _Float16* base = mg + ((size_t)tile * 1280 + row) * 8;
    half8 f[5];
    if (sub < 3) {
        plane_gather_fast(sub, X, Y, Z, pl_t, l_t, f);
        #pragma unroll
        for (int j = 0; j < 5; ++j)
            *(half8*)(base + (size_t)(sub * 5 + j) * 512) = f[j];
    } else {
        embed_chunks(X, Y, Z, f);
        #pragma unroll
        for (int j = 0; j < 5; ++j)
            *(half8*)(base + (size_t)(15 + j) * 512) = f[j];
    }
}

// ---- T0 MLP: A-frags direct from global, LDS only for h (swizzled) --------

__global__ __launch_bounds__(256, 4)
void mlp_k(const _Float16* __restrict__ mg,
           const _Float16* __restrict__ w1s, const _Float16* __restrict__ w2s,
           const float* __restrict__ b1, const float* __restrict__ b2,
           float* __restrict__ out)
{
    __shared__ _Float16 h_lds[TILE_M * 256];           // 32768 B, XOR-swizzled
    const int tid = threadIdx.x, blk = blockIdx.x;
    const int lane = tid & 63, wv = tid >> 6, l15 = lane & 15, quad = lane >> 4;
    const _Float16* tg = mg + (size_t)blk * (1280 * 8);

    // ---------------- layer 1: [64x160] @ [160x256] -> h -------------------
    floatx4 acc1[4][4];
    #pragma unroll
    for (int mt = 0; mt < 4; ++mt)
        #pragma unroll
        for (int nt = 0; nt < 4; ++nt)
            acc1[mt][nt] = (floatx4){0.f, 0.f, 0.f, 0.f};

    #pragma unroll
    for (int s = 0; s < 5; ++s) {
        half8 a[4], b[4];
        #pragma unroll
        for (int mt = 0; mt < 4; ++mt)
            a[mt] = *(const half8*)(tg + ((size_t)((s * 4 + quad) * 64) + mt * 16 + l15) * 8);
        #pragma unroll
        for (int nt = 0; nt < 4; ++nt)
            b[nt] = *(const half8*)(w1s + ((size_t)((s * 4 + quad) * 256) + wv * 64 + nt * 16 + l15) * 8);
        #pragma unroll
        for (int mt = 0; mt < 4; ++mt)
            #pragma unroll
            for (int nt = 0; nt < 4; ++nt)
                acc1[mt][nt] = __builtin_amdgcn_mfma_f32_16x16x32_f16(a[mt], b[nt], acc1[mt][nt], 0, 0, 0);
    }
    // epilogue: softplus(100z)/100, write h (f16) to swizzled LDS
    #pragma unroll
    for (int nt = 0; nt < 4; ++nt) {
        const int n = wv * 64 + nt * 16 + l15;
        const float bias = b1[n];
        #pragma unroll
        for (int mt = 0; mt < 4; ++mt) {
            #pragma unroll
            for (int r = 0; r < 4; ++r) {
                const int rowh = mt * 16 + quad * 4 + r;
                const float z = 100.f * (acc1[mt][nt][r] + bias);
                h_lds[(rowh * 256 + n) ^ ((rowh & 7) << 3)] = (_Float16)(softplus100(z) * 0.01f);
            }
        }
    }
    __syncthreads();

    // ---------------- layer 2: [64x256] @ [256x144] -> out -----------------
    floatx4 acc2[9];
    #pragma unroll
    for (int nt = 0; nt < 9; ++nt) acc2[nt] = (floatx4){0.f, 0.f, 0.f, 0.f};

    const int row2 = wv * 16 + l15;
    #pragma unroll
    for (int s = 0; s < 8; ++s) {
        const half8 a = *(const half8*)&h_lds[(row2 * 256 + s * 32 + quad * 8) ^ ((row2 & 7) << 3)];
        #pragma unroll
        for (int nt = 0; nt < 9; ++nt) {
            const half8 b = *(const half8*)(w2s + ((size_t)((s * 4 + quad) * 144) + nt * 16 + l15) * 8);
            acc2[nt] = __builtin_amdgcn_mfma_f32_16x16x32_f16(a, b, acc2[nt], 0, 0, 0);
        }
    }
    const int m_lo = wv * 16 + quad * 4;
    #pragma unroll
    for (int nt = 0; nt < 9; ++nt) {
        const int n = nt * 16 + l15;
        if (n < OUT_CH) {
            const float bias = b2[n];
            #pragma unroll
            for (int r = 0; r < 4; ++r) {
                const size_t gm = (size_t)blk * TILE_M + m_lo + r;
                out[gm * OUT_CH + n] = acc2[nt][r] + bias;
            }
        }
    }
}

// ---- T1/T2 fallback: fused kernel with new layout -------------------------

template <int FASTMODE>
__global__ __launch_bounds__(256, 3)
void tsdf_fused40_k(const float* __restrict__ xyz,
                    const float* __restrict__ planes, const float* __restrict__ lines,
                    const _Float16* __restrict__ pl_t, const _Float16* __restrict__ l_t,
                    const _Float16* __restrict__ w1s, const _Float16* __restrict__ w2s,
                    const float* __restrict__ b1, const float* __restrict__ b2,
                    float* __restrict__ out)
{
    __shared__ _Float16 mlp_lds[TILE_M * 160];         // 20480 B, swz (row&3)
    __shared__ _Float16 h_lds[TILE_M * 256];           // 32768 B, swz (row&7)
    const int tid = threadIdx.x, blk = blockIdx.x;

    {
        const int p = tid >> 2, sub = tid & 3;
        const size_t gp = (size_t)blk * TILE_M + p;
        const float X = xyz[gp * 3 + 0];
        const float Y = xyz[gp * 3 + 1];
        const float Z = xyz[gp * 3 + 2];
        half8 f[5];
        int c0;
        if (sub < 3) {
            if (FASTMODE) plane_gather_fast(sub, X, Y, Z, pl_t, l_t, f);
            else          plane_gather_slow(sub, X, Y, Z, planes, lines, f);
            c0 = sub * 5;
        } else {
            embed_chunks(X, Y, Z, f);
            c0 = 15;
        }
        #pragma unroll
        for (int j = 0; j < 5; ++j) {
            const int idx = (p * 160 + (c0 + j) * 8) ^ ((p & 3) << 3);
            *(half8*)&mlp_lds[idx] = f[j];
        }
    }
    __syncthreads();

    const int lane = tid & 63, wv = tid >> 6, l15 = lane & 15, quad = lane >> 4;
    floatx4 acc1[4][4];
    #pragma unroll
    for (int mt = 0; mt < 4; ++mt)
        #pragma unroll
        for (int nt = 0; nt < 4; ++nt)
            acc1[mt][nt] = (floatx4){0.f, 0.f, 0.f, 0.f};

    #pragma unroll
    for (int s = 0; s < 5; ++s) {
        half8 a[4], b[4];
        #pragma unroll
        for (int mt = 0; mt < 4; ++mt) {
            const int row = mt * 16 + l15;
            a[mt] = *(const half8*)&mlp_lds[(row * 160 + s * 32 + quad * 8) ^ ((row & 3) << 3)];
        }
        #pragma unroll
        for (int nt = 0; nt < 4; ++nt)
            b[nt] = *(const half8*)(w1s + ((size_t)((s * 4 + quad) * 256) + wv * 64 + nt * 16 + l15) * 8);
        #pragma unroll
        for (int mt = 0; mt < 4; ++mt)
            #pragma unroll
            for (int nt = 0; nt < 4; ++nt)
                acc1[mt][nt] = __builtin_amdgcn_mfma_f32_16x16x32_f16(a[mt], b[nt], acc1[mt][nt], 0, 0, 0);
    }
    #pragma unroll
    for (int nt = 0; nt < 4; ++nt) {
        const int n = wv * 64 + nt * 16 + l15;
        const float bias = b1[n];
        #pragma unroll
        for (int mt = 0; mt < 4; ++mt) {
            #pragma unroll
            for (int r = 0; r < 4; ++r) {
                const int rowh = mt * 16 + quad * 4 + r;
                const float z = 100.f * (acc1[mt][nt][r] + bias);
                h_lds[(rowh * 256 + n) ^ ((rowh & 7) << 3)] = (_Float16)(softplus100(z) * 0.01f);
            }
        }
    }
    __syncthreads();

    floatx4 acc2[9];
    #pragma unroll
    for (int nt = 0; nt < 9; ++nt) acc2[nt] = (floatx4){0.f, 0.f, 0.f, 0.f};

    const int row2 = wv * 16 + l15;
    #pragma unroll
    for (int s = 0; s < 8; ++s) {
        const half8 a = *(const half8*)&h_lds[(row2 * 256 + s * 32 + quad * 8) ^ ((row2 & 7) << 3)];
        #pragma unroll
        for (int nt = 0; nt < 9; ++nt) {
            const half8 b = *(const half8*)(w2s + ((size_t)((s * 4 + quad) * 144) + nt * 16 + l15) * 8);
            acc2[nt] = __builtin_amdgcn_mfma_f32_16x16x32_f16(a, b, acc2[nt], 0, 0, 0);
        }
    }
    const int m_lo = wv * 16 + quad * 4;
    #pragma unroll
    for (int nt = 0; nt < 9; ++nt) {
        const int n = nt * 16 + l15;
        if (n < OUT_CH) {
            const float bias = b2[n];
            #pragma unroll
            for (int r = 0; r < 4; ++r) {
                const size_t gm = (size_t)blk * TILE_M + m_lo + r;
                out[gm * OUT_CH + n] = acc2[nt][r] + bias;
            }
        }
    }
}

// ---- launch ---------------------------------------------------------------

extern "C" void kernel_launch(void* const* d_in, const int* in_sizes, int n_in,
                              void* d_out, int out_size, void* d_ws, size_t ws_size,
                              hipStream_t stream) {
    const float* xyz    = (const float*)d_in[0];
    const float* planes = (const float*)d_in[1];
    const float* lines  = (const float*)d_in[2];
    const float* w1     = (const float*)d_in[3];
    const float* b1     = (const float*)d_in[4];
    const float* w2     = (const float*)d_in[5];
    const float* b2     = (const float*)d_in[6];
    float* out = (float*)d_out;
    char* ws = (char*)d_ws;

    _Float16* w1s  = (_Float16*)(ws + OFF_W1S);
    _Float16* w2s  = (_Float16*)(ws + OFF_W2S);
    _Float16* l_t  = (_Float16*)(ws + OFF_LT);
    _Float16* pl_t = (_Float16*)(ws + OFF_PLT);
    _Float16* mg   = (_Float16*)(ws + OFF_MLP);

    const bool t0 = (ws_size >= NEED_T0);
    const bool t1 = (ws_size >= NEED_T1);

    prep_small_k<<<NB_W1 + NB_W2 + NB_L, 256, 0, stream>>>(w1, w2, lines, w1s, w2s, l_t);

    if (t0) {
        prep_planes_k<<<(3 * GRES * GRES + 255) / 256, 256, 0, stream>>>(planes, pl_t);
        sampler_k<<<NPTS / TILE_M, 256, 0, stream>>>(xyz, pl_t, l_t, mg);
        mlp_k<<<NPTS / TILE_M, 256, 0, stream>>>(mg, w1s, w2s, b1, b2, out);
    } else if (t1) {
        prep_planes_k<<<(3 * GRES * GRES + 255) / 256, 256, 0, stream>>>(planes, pl_t);
        tsdf_fused40_k<1><<<NPTS / TILE_M, 256, 0, stream>>>(
            xyz, planes, lines, pl_t, l_t, w1s, w2s, b1, b2, out);
    } else {
        tsdf_fused40_k<0><<<NPTS / TILE_M, 256, 0, stream>>>(
            xyz, planes, lines, pl_t, l_t, w1s, w2s, b1, b2, out);
    }
}

// Round 2
// 552.570 us; speedup vs baseline: 1.2318x; 1.2318x over previous
//
#include <hip/hip_runtime.h>
#include <cstdint>
#include <cstddef>

// ---------------------------------------------------------------------------
// TensoSDF shape renderer: tri-plane sample + embed -> MLP(129->256->129)
// R3: re-fused single kernel (split in R2 regressed: mg round-trip latency +
// lost cross-block phase overlap). Keeps R2's validated improvements:
//  - planes & lines padded to NCP=40 channels -> 16B gather loads, half8 folds
//  - LDS XOR-swizzled, no padding: 20.5KB mlp_in + 32KB h = 52.25KB
//    -> 3 blocks/CU (was 2 at 55.3KB)
//  - k-map: k<120 -> feat m=k/40,c=k%40 (c<36 valid, ref 21+m*36+c)
//           120<=k<141 -> embed ref k-120 ; else zero-weight
// ---------------------------------------------------------------------------

using half2v  = __attribute__((ext_vector_type(2))) _Float16;
using half4   = __attribute__((ext_vector_type(4))) _Float16;
using half8   = __attribute__((ext_vector_type(8))) _Float16;
using floatx4 = __attribute__((ext_vector_type(4))) float;

#define NPTS    524288
#define GRES    300
#define NCOMP   36
#define NCP     40
#define SDFD    256
#define IN_CH   129
#define OUT_CH  129
#define TILE_M  64

// workspace layout (bytes), all 16B aligned
#define OFF_W1S 0
#define SZ_W1S  (5*4*256*8*2)               // 81920 : w1 swizzled f16 [c16][n=256][j=8]
#define OFF_W2S (OFF_W1S + SZ_W1S)
#define SZ_W2S  (8*4*144*8*2)               // 73728 : w2 swizzled f16
#define OFF_LT  (OFF_W2S + SZ_W2S)
#define SZ_LT   (3*GRES*NCP*2)              // 72000 : lines ch-last padded f16
#define OFF_PLT (OFF_LT + SZ_LT)
#define SZ_PLT  ((size_t)3*GRES*GRES*NCP*2) // 21.6MB: planes ch-last padded f16
#define NEED_FAST ((size_t)OFF_PLT + SZ_PLT)

// ---- prep kernels ---------------------------------------------------------

__global__ void prep_planes_k(const float* __restrict__ planes, _Float16* __restrict__ pl_t) {
    int idx = blockIdx.x * 256 + threadIdx.x;           // (m*300+y)*300+x
    if (idx >= 3 * GRES * GRES) return;
    int x = idx % GRES; int t = idx / GRES; int y = t % GRES; int m = t / GRES;
    _Float16* dst = pl_t + (size_t)idx * NCP;
    const float* src = planes + (size_t)m * NCOMP * GRES * GRES + (size_t)y * GRES + x;
    #pragma unroll
    for (int j = 0; j < 5; ++j) {
        half8 o;
        #pragma unroll
        for (int e = 0; e < 8; ++e) {
            int c = j * 8 + e;
            o[e] = (c < NCOMP) ? (_Float16)src[(size_t)c * GRES * GRES] : (_Float16)0.f;
        }
        *(half8*)(dst + j * 8) = o;
    }
}

#define NB_W1 ((5*4*256*8 + 255)/256)      // 160
#define NB_W2 ((8*4*144*8 + 255)/256)      // 144
#define NB_L  ((3*GRES + 255)/256)         // 4
__global__ void prep_small_k(const float* __restrict__ w1, const float* __restrict__ w2,
                             const float* __restrict__ lines,
                             _Float16* __restrict__ w1s, _Float16* __restrict__ w2s,
                             _Float16* __restrict__ l_t) {
    int b = blockIdx.x;
    if (b < NB_W1) {
        int t = b * 256 + threadIdx.x;                   // < 40960 exactly
        int j = t & 7; int n = (t >> 3) & 255; int q = t >> 11;
        int k = q * 8 + j;                               // 0..159
        float v = 0.f;
        if (k < 120) {
            int m = k / 40, c = k % 40;
            if (c < NCOMP) v = w1[n * IN_CH + 21 + m * NCOMP + c];
        } else if (k < 141) {
            v = w1[n * IN_CH + (k - 120)];
        }
        w1s[t] = (_Float16)v;
    } else if (b < NB_W1 + NB_W2) {
        int t = (b - NB_W1) * 256 + threadIdx.x;
        if (t >= 8*4*144*8) return;
        int j = t & 7; int r = t >> 3; int n = r % 144; int q = r / 144;
        int k = q * 8 + j;                               // 0..255
        float v = (n < OUT_CH) ? w2[n * SDFD + k] : 0.f;
        w2s[t] = (_Float16)v;
    } else {
        int idx = (b - NB_W1 - NB_W2) * 256 + threadIdx.x;   // m*300+z
        if (idx >= 3 * GRES) return;
        int z = idx % GRES; int m = idx / GRES;
        _Float16* dst = l_t + (size_t)idx * NCP;
        const float* src = lines + ((size_t)m * NCOMP) * GRES + z;
        #pragma unroll
        for (int c = 0; c < NCOMP; ++c) dst[c] = (_Float16)src[(size_t)c * GRES];
        dst[36] = dst[37] = dst[38] = dst[39] = (_Float16)0.f;
    }
}

// ---- device helpers -------------------------------------------------------

__device__ __forceinline__ float softplus100(float z) {
    return fmaxf(z, 0.f) + __logf(1.f + __expf(-fabsf(z)));
}

__device__ __forceinline__ void plane_coords(int m, float X, float Y, float Z,
                                             int& x0, int& y0, int& z0,
                                             float& tx, float& ty, float& tz) {
    const float px = (m == 2) ? Y : X;
    const float py = (m == 0) ? Y : Z;
    const float pz = (m == 0) ? Z : ((m == 1) ? Y : X);
    float fx = (px + 1.f) * 0.5f * 299.f;
    float fy = (py + 1.f) * 0.5f * 299.f;
    float fz = (pz + 1.f) * 0.5f * 299.f;
    x0 = (int)floorf(fx); x0 = x0 < 0 ? 0 : (x0 > 298 ? 298 : x0);
    y0 = (int)floorf(fy); y0 = y0 < 0 ? 0 : (y0 > 298 ? 298 : y0);
    z0 = (int)floorf(fz); z0 = z0 < 0 ? 0 : (z0 > 298 ? 298 : z0);
    tx = fx - (float)x0; ty = fy - (float)y0; tz = fz - (float)z0;
}

// fast gather: NCP=40 channel-last layout; corner-pair = 160B contiguous
__device__ __forceinline__ void plane_gather_fast(
    int m, float X, float Y, float Z,
    const _Float16* __restrict__ pl_t, const _Float16* __restrict__ l_t,
    half8 f[5])
{
    int x0, y0, z0; float tx, ty, tz;
    plane_coords(m, X, Y, Z, x0, y0, z0, tx, ty, tz);
    const _Float16 h00 = (_Float16)((1.f - tx) * (1.f - ty));
    const _Float16 h01 = (_Float16)(tx * (1.f - ty));
    const _Float16 h10 = (_Float16)((1.f - tx) * ty);
    const _Float16 h11 = (_Float16)(tx * ty);
    const _Float16 hl0 = (_Float16)(1.f - tz), hl1 = (_Float16)tz;
    const half8 W00 = {h00,h00,h00,h00,h00,h00,h00,h00};
    const half8 W01 = {h01,h01,h01,h01,h01,h01,h01,h01};
    const half8 W10 = {h10,h10,h10,h10,h10,h10,h10,h10};
    const half8 W11 = {h11,h11,h11,h11,h11,h11,h11,h11};
    const half8 WL0 = {hl0,hl0,hl0,hl0,hl0,hl0,hl0,hl0};
    const half8 WL1 = {hl1,hl1,hl1,hl1,hl1,hl1,hl1,hl1};
    const _Float16* r0 = pl_t + ((size_t)(m * GRES + y0) * GRES + x0) * NCP;  // (y0,x0|x0+1)
    const _Float16* r1 = r0 + (size_t)GRES * NCP;                              // (y0+1, ...)
    const _Float16* lb = l_t + (size_t)(m * GRES + z0) * NCP;                  // (z0|z0+1)
    half8 a0[10], a1[10], al[10];
    #pragma unroll
    for (int j = 0; j < 10; ++j) a0[j] = *(const half8*)(r0 + 8 * j);
    #pragma unroll
    for (int j = 0; j < 10; ++j) a1[j] = *(const half8*)(r1 + 8 * j);
    half8 pf[5];
    #pragma unroll
    for (int j = 0; j < 5; ++j)
        pf[j] = a0[j] * W00 + a0[j + 5] * W01 + a1[j] * W10 + a1[j + 5] * W11;
    #pragma unroll
    for (int j = 0; j < 10; ++j) al[j] = *(const half8*)(lb + 8 * j);
    #pragma unroll
    for (int j = 0; j < 5; ++j) {
        half8 lf = al[j] * WL0 + al[j + 5] * WL1;
        f[j] = pf[j] * lf;
    }
}

// slow gather: raw f32 planes/lines (fallback when workspace too small)
__device__ __forceinline__ void plane_gather_slow(
    int m, float X, float Y, float Z,
    const float* __restrict__ planes, const float* __restrict__ lines,
    half8 f[5])
{
    int x0, y0, z0; float tx, ty, tz;
    plane_coords(m, X, Y, Z, x0, y0, z0, tx, ty, tz);
    const float w00 = (1.f - tx) * (1.f - ty), w01 = tx * (1.f - ty);
    const float w10 = (1.f - tx) * ty,         w11 = tx * ty;
    const float lw0 = 1.f - tz, lw1 = tz;
    #pragma unroll
    for (int j = 0; j < 5; ++j) f[j] = (half8){0,0,0,0,0,0,0,0};
    const float* pb = planes + (size_t)m * NCOMP * GRES * GRES;
    #pragma unroll
    for (int c = 0; c < NCOMP; ++c) {
        const float* pc = pb + (size_t)c * GRES * GRES + (size_t)y0 * GRES + x0;
        const float* lc = lines + ((size_t)m * NCOMP + c) * GRES + z0;
        float pf = pc[0] * w00 + pc[1] * w01 + pc[GRES] * w10 + pc[GRES + 1] * w11;
        float lf = lc[0] * lw0 + lc[1] * lw1;
        f[c >> 3][c & 7] = (_Float16)(pf * lf);
    }
}

// embed -> chunks c16=15..19 (k=120..159); zeros beyond k=140
__device__ __forceinline__ void embed_chunks(float X, float Y, float Z, half8 e[5]) {
    const float v3[3] = {X, Y, Z};
    _Float16 s[3][3], c[3][3];
    #pragma unroll
    for (int d = 0; d < 3; ++d) {
        float fm = 1.f;
        #pragma unroll
        for (int q = 0; q < 3; ++q) {
            const float a = v3[d] * fm;
            s[d][q] = (_Float16)__sinf(a);
            c[d][q] = (_Float16)__cosf(a);
            fm *= 2.f;
        }
    }
    const _Float16 z0 = (_Float16)0.f;
    e[0] = (half8){(_Float16)X, (_Float16)Y, (_Float16)Z, s[0][0], s[0][1], s[0][2], s[1][0], s[1][1]};
    e[1] = (half8){s[1][2], s[2][0], s[2][1], s[2][2], c[0][0], c[0][1], c[0][2], c[1][0]};
    e[2] = (half8){c[1][1], c[1][2], c[2][0], c[2][1], c[2][2], z0, z0, z0};
    e[3] = (half8){z0,z0,z0,z0,z0,z0,z0,z0};
    e[4] = (half8){z0,z0,z0,z0,z0,z0,z0,z0};
}

// ---- fused kernel ---------------------------------------------------------
// LDS: mlp_in [64][160] f16 swz(row&3), h [64][256] f16 swz(row&7) = 52.25KB
// -> 3 blocks/CU (LDS-limited), 12 waves/CU.

template <int FASTMODE>
__global__ __launch_bounds__(256, 3)
void tsdf_fused40_k(const float* __restrict__ xyz,
                    const float* __restrict__ planes, const float* __restrict__ lines,
                    const _Float16* __restrict__ pl_t, const _Float16* __restrict__ l_t,
                    const _Float16* __restrict__ w1s, const _Float16* __restrict__ w2s,
                    const float* __restrict__ b1, const float* __restrict__ b2,
                    float* __restrict__ out)
{
    __shared__ _Float16 mlp_lds[TILE_M * 160];         // 20480 B, swz (row&3)
    __shared__ _Float16 h_lds[TILE_M * 256];           // 32768 B, swz (row&7)
    const int tid = threadIdx.x, blk = blockIdx.x;

    // ---------------- phase 1: sampling + embed into LDS -------------------
    {
        const int p = tid >> 2, sub = tid & 3;
        const size_t gp = (size_t)blk * TILE_M + p;
        const float X = xyz[gp * 3 + 0];
        const float Y = xyz[gp * 3 + 1];
        const float Z = xyz[gp * 3 + 2];
        half8 f[5];
        int c0;
        if (sub < 3) {
            if (FASTMODE) plane_gather_fast(sub, X, Y, Z, pl_t, l_t, f);
            else          plane_gather_slow(sub, X, Y, Z, planes, lines, f);
            c0 = sub * 5;
        } else {
            embed_chunks(X, Y, Z, f);
            c0 = 15;
        }
        #pragma unroll
        for (int j = 0; j < 5; ++j) {
            const int idx = (p * 160 + (c0 + j) * 8) ^ ((p & 3) << 3);
            *(half8*)&mlp_lds[idx] = f[j];
        }
    }
    __syncthreads();

    const int lane = tid & 63, wv = tid >> 6, l15 = lane & 15, quad = lane >> 4;

    // ---------------- layer 1: [64x160] @ [160x256] -> h -------------------
    floatx4 acc1[4][4];
    #pragma unroll
    for (int mt = 0; mt < 4; ++mt)
        #pragma unroll
        for (int nt = 0; nt < 4; ++nt)
            acc1[mt][nt] = (floatx4){0.f, 0.f, 0.f, 0.f};

    #pragma unroll
    for (int s = 0; s < 5; ++s) {
        half8 a[4], b[4];
        #pragma unroll
        for (int mt = 0; mt < 4; ++mt) {
            const int row = mt * 16 + l15;
            a[mt] = *(const half8*)&mlp_lds[(row * 160 + s * 32 + quad * 8) ^ ((row & 3) << 3)];
        }
        #pragma unroll
        for (int nt = 0; nt < 4; ++nt)
            b[nt] = *(const half8*)(w1s + ((size_t)((s * 4 + quad) * 256) + wv * 64 + nt * 16 + l15) * 8);
        #pragma unroll
        for (int mt = 0; mt < 4; ++mt)
            #pragma unroll
            for (int nt = 0; nt < 4; ++nt)
                acc1[mt][nt] = __builtin_amdgcn_mfma_f32_16x16x32_f16(a[mt], b[nt], acc1[mt][nt], 0, 0, 0);
    }
    // epilogue: softplus(100z)/100, write h (f16) to swizzled LDS
    #pragma unroll
    for (int nt = 0; nt < 4; ++nt) {
        const int n = wv * 64 + nt * 16 + l15;
        const float bias = b1[n];
        #pragma unroll
        for (int mt = 0; mt < 4; ++mt) {
            #pragma unroll
            for (int r = 0; r < 4; ++r) {
                const int rowh = mt * 16 + quad * 4 + r;
                const float z = 100.f * (acc1[mt][nt][r] + bias);
                h_lds[(rowh * 256 + n) ^ ((rowh & 7) << 3)] = (_Float16)(softplus100(z) * 0.01f);
            }
        }
    }
    __syncthreads();

    // ---------------- layer 2: [64x256] @ [256x144] -> out -----------------
    floatx4 acc2[9];
    #pragma unroll
    for (int nt = 0; nt < 9; ++nt) acc2[nt] = (floatx4){0.f, 0.f, 0.f, 0.f};

    const int row2 = wv * 16 + l15;
    #pragma unroll
    for (int s = 0; s < 8; ++s) {
        const half8 a = *(const half8*)&h_lds[(row2 * 256 + s * 32 + quad * 8) ^ ((row2 & 7) << 3)];
        #pragma unroll
        for (int nt = 0; nt < 9; ++nt) {
            const half8 b = *(const half8*)(w2s + ((size_t)((s * 4 + quad) * 144) + nt * 16 + l15) * 8);
            acc2[nt] = __builtin_amdgcn_mfma_f32_16x16x32_f16(a, b, acc2[nt], 0, 0, 0);
        }
    }
    const int m_lo = wv * 16 + quad * 4;
    #pragma unroll
    for (int nt = 0; nt < 9; ++nt) {
        const int n = nt * 16 + l15;
        if (n < OUT_CH) {
            const float bias = b2[n];
            #pragma unroll
            for (int r = 0; r < 4; ++r) {
                const size_t gm = (size_t)blk * TILE_M + m_lo + r;
                out[gm * OUT_CH + n] = acc2[nt][r] + bias;
            }
        }
    }
}

// ---- launch ---------------------------------------------------------------

extern "C" void kernel_launch(void* const* d_in, const int* in_sizes, int n_in,
                              void* d_out, int out_size, void* d_ws, size_t ws_size,
                              hipStream_t stream) {
    const float* xyz    = (const float*)d_in[0];
    const float* planes = (const float*)d_in[1];
    const float* lines  = (const float*)d_in[2];
    const float* w1     = (const float*)d_in[3];
    const float* b1     = (const float*)d_in[4];
    const float* w2     = (const float*)d_in[5];
    const float* b2     = (const float*)d_in[6];
    float* out = (float*)d_out;
    char* ws = (char*)d_ws;

    _Float16* w1s  = (_Float16*)(ws + OFF_W1S);
    _Float16* w2s  = (_Float16*)(ws + OFF_W2S);
    _Float16* l_t  = (_Float16*)(ws + OFF_LT);
    _Float16* pl_t = (_Float16*)(ws + OFF_PLT);

    const bool fast = (ws_size >= NEED_FAST);

    prep_small_k<<<NB_W1 + NB_W2 + NB_L, 256, 0, stream>>>(w1, w2, lines, w1s, w2s, l_t);

    if (fast) {
        prep_planes_k<<<(3 * GRES * GRES + 255) / 256, 256, 0, stream>>>(planes, pl_t);
        tsdf_fused40_k<1><<<NPTS / TILE_M, 256, 0, stream>>>(
            xyz, planes, lines, pl_t, l_t, w1s, w2s, b1, b2, out);
    } else {
        tsdf_fused40_k<0><<<NPTS / TILE_M, 256, 0, stream>>>(
            xyz, planes, lines, pl_t, l_t, w1s, w2s, b1, b2, out);
    }
}